// Round 3
// baseline (178.875 us; speedup 1.0000x reference)
//
#include <hip/hip_runtime.h>
#include <hip/hip_bf16.h>
#include <hip/hip_cooperative_groups.h>
#include <math.h>

namespace cg = cooperative_groups;

#define N 4096
#define D 128
#define POS_W 2.0f
#define NEG_W 40.0f
#define MARGIN 0.1f
#define THRESH 0.5f

typedef __bf16 bf16x8 __attribute__((ext_vector_type(8)));
typedef float f32x4 __attribute__((ext_vector_type(4)));
typedef unsigned int uint32;

// order-preserving float<->uint encoding (for atomicMin/Max)
__device__ __forceinline__ uint32 enc_f(float f) {
  uint32 u = __float_as_uint(f);
  return (u & 0x80000000u) ? ~u : (u | 0x80000000u);
}
__device__ __forceinline__ float dec_f(uint32 e) {
  uint32 u = (e & 0x80000000u) ? (e & 0x7FFFFFFFu) : ~e;
  return __uint_as_float(u);
}

// One cooperative kernel: normalize -> S-tile in registers -> min/max mine ->
// grid sync -> exp sums over the SAME registers -> finalize.
// grid = 256 blocks (1/CU, LDS-bound), block = 512 threads (8 waves).
__global__ __launch_bounds__(512, 2) void k_fused(
    const float* __restrict__ x, const int* __restrict__ labels,
    ushort* __restrict__ xn, uint32* __restrict__ mp_enc,
    uint32* __restrict__ mn_enc, float* __restrict__ rp,
    float* __restrict__ rn, float* __restrict__ out) {
  __shared__ ushort Abuf[256 * 128];  // 64 KB bf16 [row][k], XOR-swizzled
  __shared__ ushort Bbuf[256 * 128];  // 64 KB
  __shared__ int labi[256], labj[256];
  __shared__ float redA[256][4], redB[256][4];
  __shared__ float mpS[256], mnS[256];
  __shared__ float fin[3][8];

  cg::grid_group grid = cg::this_grid();

  const int t = threadIdx.x;
  const int wv = t >> 6, lane = t & 63;
  const int bid = blockIdx.x;

  // ---------- phase 1: L2-normalize rows -> bf16; init accumulators ----------
#pragma unroll
  for (int rr = 0; rr < 2; ++rr) {
    const int row = bid * 16 + wv * 2 + rr;
    const float2 v = *(const float2*)&x[row * D + lane * 2];
    float ss = v.x * v.x + v.y * v.y;
#pragma unroll
    for (int off = 32; off; off >>= 1) ss += __shfl_xor(ss, off);
    const float rnorm = rsqrtf(ss);
    __hip_bfloat162 o;
    o.x = __float2bfloat16(v.x * rnorm);
    o.y = __float2bfloat16(v.y * rnorm);
    *(__hip_bfloat162*)&xn[row * D + lane * 2] = o;
  }
  {
    const int gi = bid * 512 + t;
    if (gi < N) {
      mp_enc[gi] = 0xFFFFFFFFu;  // +inf under enc ordering
      mn_enc[gi] = 0u;           // -inf under enc ordering
      rp[gi] = 0.f;
      rn[gi] = 0.f;
    }
  }
  grid.sync();

  // ---------- phase 2: stage tiles, MFMA -> S tile in registers ----------
  const int ib = bid >> 4, jb = bid & 15;
  const int i0 = ib * 256, j0 = jb * 256;

  if (t < 256) {
    labi[t] = labels[i0 + t];
    labj[t] = labels[j0 + t];
  }
  {
    const char* gA = (const char*)(xn + (size_t)i0 * D);
    const char* gB = (const char*)(xn + (size_t)j0 * D);
#pragma unroll
    for (int it = 0; it < 8; ++it) {
      const int L = (t + it * 512) * 16;         // linear byte offset in 64KB tile
      const int Ls = L ^ (((L >> 8) & 7) << 4);  // row-XOR bank swizzle
      *(f32x4*)((char*)Abuf + Ls) = *(const f32x4*)(gA + L);
      *(f32x4*)((char*)Bbuf + Ls) = *(const f32x4*)(gB + L);
    }
  }
  __syncthreads();

  const int w = t >> 6;
  const int wm = w >> 2, wn = w & 3;  // 2 x 4 wave grid; wave owns 128x64
  const int lr = lane & 15, lk = lane >> 4;

  f32x4 acc[8][4];
#pragma unroll
  for (int m = 0; m < 8; ++m)
#pragma unroll
    for (int n = 0; n < 4; ++n) acc[m][n] = (f32x4){0.f, 0.f, 0.f, 0.f};

#pragma unroll
  for (int ks = 0; ks < 4; ++ks) {
    bf16x8 af[8], bg[4];
#pragma unroll
    for (int m = 0; m < 8; ++m) {
      const int rowb = wm * 128 + m * 16 + lr;
      int off = rowb * 256 + ks * 64 + lk * 16;
      off ^= ((rowb & 7) << 4);
      af[m] = *(const bf16x8*)((const char*)Abuf + off);
    }
#pragma unroll
    for (int n = 0; n < 4; ++n) {
      const int rowb = wn * 64 + n * 16 + lr;
      int off = rowb * 256 + ks * 64 + lk * 16;
      off ^= ((rowb & 7) << 4);
      bg[n] = *(const bf16x8*)((const char*)Bbuf + off);
    }
#pragma unroll
    for (int m = 0; m < 8; ++m)
#pragma unroll
      for (int n = 0; n < 4; ++n)
        acc[m][n] = __builtin_amdgcn_mfma_f32_16x16x32_bf16(af[m], bg[n], acc[m][n], 0, 0, 0);
  }

  // C layout: col = lane&15 (B-row), row = (lane>>4)*4 + reg (A-row)
  int ljr[4];
#pragma unroll
  for (int n = 0; n < 4; ++n) ljr[n] = labj[wn * 64 + n * 16 + lr];

  // ---------- phase 3: min_pos / max_neg epilogue ----------
#pragma unroll
  for (int m = 0; m < 8; ++m) {
#pragma unroll
    for (int r = 0; r < 4; ++r) {
      const int rl = wm * 128 + m * 16 + lk * 4 + r;
      const int li = labi[rl];
      const int gi = i0 + rl;
      float pmin = 1e9f, nmax = -1e9f;
#pragma unroll
      for (int n = 0; n < 4; ++n) {
        const int cl = wn * 64 + n * 16 + lr;
        const float s = acc[m][n][r];
        if (ljr[n] == li) {
          if (gi != j0 + cl) pmin = fminf(pmin, s);
        } else {
          nmax = fmaxf(nmax, s);
        }
      }
#pragma unroll
      for (int o = 1; o < 16; o <<= 1) {
        pmin = fminf(pmin, __shfl_xor(pmin, o));
        nmax = fmaxf(nmax, __shfl_xor(nmax, o));
      }
      if (lr == 0) { redA[rl][wn] = pmin; redB[rl][wn] = nmax; }
    }
  }
  __syncthreads();
  if (t < 256) {
    atomicMin(&mp_enc[i0 + t],
              enc_f(fminf(fminf(redA[t][0], redA[t][1]), fminf(redA[t][2], redA[t][3]))));
    atomicMax(&mn_enc[i0 + t],
              enc_f(fmaxf(fmaxf(redB[t][0], redB[t][1]), fmaxf(redB[t][2], redB[t][3]))));
  }
  grid.sync();

  // ---------- phase 4: mined exp sums over the same registers ----------
  if (t < 256) {
    mpS[t] = dec_f(mp_enc[i0 + t]);
    mnS[t] = dec_f(mn_enc[i0 + t]);
  }
  __syncthreads();

#pragma unroll
  for (int m = 0; m < 8; ++m) {
#pragma unroll
    for (int r = 0; r < 4; ++r) {
      const int rl = wm * 128 + m * 16 + lk * 4 + r;
      const int li = labi[rl];
      const int gi = i0 + rl;
      const float mp = mpS[rl], mx = mnS[rl];
      float psum = 0.f, nsum = 0.f;
#pragma unroll
      for (int n = 0; n < 4; ++n) {
        const int cl = wn * 64 + n * 16 + lr;
        const float s = acc[m][n][r];
        if (ljr[n] == li) {
          if ((gi != j0 + cl) && (s - MARGIN < mx)) psum += __expf(-POS_W * (s - THRESH));
        } else {
          if (s + MARGIN > mp) nsum += __expf(NEG_W * (s - THRESH));
        }
      }
#pragma unroll
      for (int o = 1; o < 16; o <<= 1) {
        psum += __shfl_xor(psum, o);
        nsum += __shfl_xor(nsum, o);
      }
      if (lr == 0) { redA[rl][wn] = psum; redB[rl][wn] = nsum; }
    }
  }
  __syncthreads();
  if (t < 256) {
    atomicAdd(&rp[i0 + t], redA[t][0] + redA[t][1] + redA[t][2] + redA[t][3]);
    atomicAdd(&rn[i0 + t], redB[t][0] + redB[t][1] + redB[t][2] + redB[t][3]);
  }
  grid.sync();

  // ---------- phase 5: finalize (block 0 only) ----------
  if (bid == 0) {
    float sp = 0.f, sn = 0.f, sc = 0.f;
    for (int i = t; i < N; i += 512) {
      const float mp = dec_f(mp_enc[i]);
      const float mx = dec_f(mn_enc[i]);
      const float p = rp[i], ng = rn[i];
      const bool valid = (mp < 1e8f) && (mx > -1e8f) && (p > 0.f) && (ng > 0.f);
      if (valid) {
        sp += log1pf(p) * (1.0f / POS_W);
        sn += log1pf(ng) * (1.0f / NEG_W);
        sc += 1.f;
      }
    }
#pragma unroll
    for (int off = 32; off; off >>= 1) {
      sp += __shfl_xor(sp, off);
      sn += __shfl_xor(sn, off);
      sc += __shfl_xor(sc, off);
    }
    if (lane == 0) { fin[0][wv] = sp; fin[1][wv] = sn; fin[2][wv] = sc; }
    __syncthreads();
    if (t == 0) {
      float tp = 0.f, tn = 0.f, tc = 0.f;
#pragma unroll
      for (int k = 0; k < 8; ++k) { tp += fin[0][k]; tn += fin[1][k]; tc += fin[2][k]; }
      const float cnt = fmaxf(tc, 1.f);
      const float pm = tp / cnt, nm = tn / cnt;
      out[0] = pm + nm;
      out[1] = pm;
      out[2] = nm;
    }
  }
}

extern "C" void kernel_launch(void* const* d_in, const int* in_sizes, int n_in,
                              void* d_out, int out_size, void* d_ws, size_t ws_size,
                              hipStream_t stream) {
  const float* batch = (const float*)d_in[0];
  const int* labels = (const int*)d_in[1];
  float* out = (float*)d_out;

  char* ws = (char*)d_ws;
  ushort* xn = (ushort*)ws;                            // N*D bf16 = 1 MB
  uint32* mp_enc = (uint32*)(ws + (size_t)N * D * 2);  // N u32
  uint32* mn_enc = mp_enc + N;                         // N u32
  float* rp = (float*)(mn_enc + N);                    // N f32
  float* rn = rp + N;                                  // N f32

  void* args[] = {(void*)&batch, (void*)&labels, (void*)&xn, (void*)&mp_enc,
                  (void*)&mn_enc, (void*)&rp,    (void*)&rn, (void*)&out};
  hipLaunchCooperativeKernel((const void*)k_fused, dim3(256), dim3(512), args, 0, stream);
}

// Round 5
// 105.977 us; speedup vs baseline: 1.6879x; 1.6879x over previous
//
#include <hip/hip_runtime.h>
#include <hip/hip_bf16.h>
#include <math.h>

#define N 4096
#define D 128
#define NB 16  // N / 256 column blocks
#define POS_W 2.0f
#define NEG_W 40.0f
#define MARGIN 0.1f
#define THRESH 0.5f

typedef __bf16 bf16x8 __attribute__((ext_vector_type(8)));
typedef float f32x4 __attribute__((ext_vector_type(4)));

// ---------------- K1: L2-normalize rows -> bf16 ----------------
__global__ __launch_bounds__(512) void k_norm(const float* __restrict__ x,
                                              ushort* __restrict__ xn) {
  const int t = threadIdx.x, wv = t >> 6, lane = t & 63;
#pragma unroll
  for (int rr = 0; rr < 2; ++rr) {
    const int row = blockIdx.x * 16 + wv * 2 + rr;
    const float2 v = *(const float2*)&x[row * D + lane * 2];
    float ss = v.x * v.x + v.y * v.y;
#pragma unroll
    for (int off = 32; off; off >>= 1) ss += __shfl_xor(ss, off);
    const float rnorm = rsqrtf(ss);
    __hip_bfloat162 o;
    o.x = __float2bfloat16(v.x * rnorm);
    o.y = __float2bfloat16(v.y * rnorm);
    *(__hip_bfloat162*)&xn[row * D + lane * 2] = o;
  }
}

// ---------------- K2/K3: 256x256 MFMA tile; mining epilogues ----------------
// PASS 0: per-row min_pos/max_neg within this column block -> pminPart/nmaxPart[jb][row]
// PASS 1: reduce partials -> thresholds; recompute S; mined exp sums -> ppPart/npPart[jb][row]
template <int PASS>
__global__ __launch_bounds__(512, 2) void k_pass(
    const ushort* __restrict__ xn, const int* __restrict__ labels,
    float* __restrict__ pminPart, float* __restrict__ nmaxPart,
    float* __restrict__ ppPart, float* __restrict__ npPart,
    float* __restrict__ mpF, float* __restrict__ mnF) {
  __shared__ ushort Abuf[256 * 128];  // 64 KB bf16 [row][k], XOR-swizzled
  __shared__ ushort Bbuf[256 * 128];  // 64 KB
  __shared__ int labi[256], labj[256];
  __shared__ float redA[256][4], redB[256][4];
  __shared__ float mpS[256], mnS[256];

  const int t = threadIdx.x;
  const int lane = t & 63;
  const int ib = blockIdx.x >> 4, jb = blockIdx.x & 15;
  const int i0 = ib * 256, j0 = jb * 256;

  if (t < 256) {
    labi[t] = labels[i0 + t];
    labj[t] = labels[j0 + t];
  }
  // stage tiles: linear global reads, swizzled LDS writes
  {
    const char* gA = (const char*)(xn + (size_t)i0 * D);
    const char* gB = (const char*)(xn + (size_t)j0 * D);
#pragma unroll
    for (int it = 0; it < 8; ++it) {
      const int L = (t + it * 512) * 16;         // linear byte offset in 64KB tile
      const int Ls = L ^ (((L >> 8) & 7) << 4);  // row-XOR bank swizzle
      *(f32x4*)((char*)Abuf + Ls) = *(const f32x4*)(gA + L);
      *(f32x4*)((char*)Bbuf + Ls) = *(const f32x4*)(gB + L);
    }
  }
  if (PASS == 1 && t < 256) {
    // reduce 16 column-block partials -> global thresholds for rows i0..i0+255
    float mp = 1e9f, mx = -1e9f;
#pragma unroll
    for (int b = 0; b < NB; ++b) {
      mp = fminf(mp, pminPart[b * N + i0 + t]);
      mx = fmaxf(mx, nmaxPart[b * N + i0 + t]);
    }
    mpS[t] = mp;
    mnS[t] = mx;
    if (jb == 0) { mpF[i0 + t] = mp; mnF[i0 + t] = mx; }
  }
  __syncthreads();

  const int w = t >> 6;
  const int wm = w >> 2, wn = w & 3;  // 2 x 4 wave grid; wave owns 128x64
  const int lr = lane & 15, lk = lane >> 4;

  f32x4 acc[8][4];
#pragma unroll
  for (int m = 0; m < 8; ++m)
#pragma unroll
    for (int n = 0; n < 4; ++n) acc[m][n] = (f32x4){0.f, 0.f, 0.f, 0.f};

#pragma unroll
  for (int ks = 0; ks < 4; ++ks) {
    bf16x8 af[8], bg[4];
#pragma unroll
    for (int m = 0; m < 8; ++m) {
      const int rowb = wm * 128 + m * 16 + lr;
      int off = rowb * 256 + ks * 64 + lk * 16;
      off ^= ((rowb & 7) << 4);
      af[m] = *(const bf16x8*)((const char*)Abuf + off);
    }
#pragma unroll
    for (int n = 0; n < 4; ++n) {
      const int rowb = wn * 64 + n * 16 + lr;
      int off = rowb * 256 + ks * 64 + lk * 16;
      off ^= ((rowb & 7) << 4);
      bg[n] = *(const bf16x8*)((const char*)Bbuf + off);
    }
#pragma unroll
    for (int m = 0; m < 8; ++m)
#pragma unroll
      for (int n = 0; n < 4; ++n)
        acc[m][n] = __builtin_amdgcn_mfma_f32_16x16x32_bf16(af[m], bg[n], acc[m][n], 0, 0, 0);
  }

  // C layout: col = lane&15 (B-row), row = (lane>>4)*4 + reg (A-row)
  int ljr[4];
#pragma unroll
  for (int n = 0; n < 4; ++n) ljr[n] = labj[wn * 64 + n * 16 + lr];

#pragma unroll
  for (int m = 0; m < 8; ++m) {
#pragma unroll
    for (int r = 0; r < 4; ++r) {
      const int rl = wm * 128 + m * 16 + lk * 4 + r;  // local row
      const int li = labi[rl];
      const int gi = i0 + rl;
      if (PASS == 0) {
        float pmin = 1e9f, nmax = -1e9f;
#pragma unroll
        for (int n = 0; n < 4; ++n) {
          const int cl = wn * 64 + n * 16 + lr;
          const float s = acc[m][n][r];
          if (ljr[n] == li) {
            if (gi != j0 + cl) pmin = fminf(pmin, s);
          } else {
            nmax = fmaxf(nmax, s);
          }
        }
#pragma unroll
        for (int o = 1; o < 16; o <<= 1) {
          pmin = fminf(pmin, __shfl_xor(pmin, o));
          nmax = fmaxf(nmax, __shfl_xor(nmax, o));
        }
        if (lr == 0) { redA[rl][wn] = pmin; redB[rl][wn] = nmax; }
      } else {
        const float mp = mpS[rl], mx = mnS[rl];
        float psum = 0.f, nsum = 0.f;
#pragma unroll
        for (int n = 0; n < 4; ++n) {
          const int cl = wn * 64 + n * 16 + lr;
          const float s = acc[m][n][r];
          if (ljr[n] == li) {
            if ((gi != j0 + cl) && (s - MARGIN < mx)) psum += __expf(-POS_W * (s - THRESH));
          } else {
            if (s + MARGIN > mp) nsum += __expf(NEG_W * (s - THRESH));
          }
        }
#pragma unroll
        for (int o = 1; o < 16; o <<= 1) {
          psum += __shfl_xor(psum, o);
          nsum += __shfl_xor(nsum, o);
        }
        if (lr == 0) { redA[rl][wn] = psum; redB[rl][wn] = nsum; }
      }
    }
  }
  __syncthreads();
  if (t < 256) {
    if (PASS == 0) {
      pminPart[jb * N + i0 + t] =
          fminf(fminf(redA[t][0], redA[t][1]), fminf(redA[t][2], redA[t][3]));
      nmaxPart[jb * N + i0 + t] =
          fmaxf(fmaxf(redB[t][0], redB[t][1]), fmaxf(redB[t][2], redB[t][3]));
    } else {
      ppPart[jb * N + i0 + t] = redA[t][0] + redA[t][1] + redA[t][2] + redA[t][3];
      npPart[jb * N + i0 + t] = redB[t][0] + redB[t][1] + redB[t][2] + redB[t][3];
    }
  }
}

// ---------------- K4: per-row terms ----------------
__global__ __launch_bounds__(256) void k_rowterms(
    const float* __restrict__ ppPart, const float* __restrict__ npPart,
    const float* __restrict__ mpF, const float* __restrict__ mnF,
    float* __restrict__ row_pos, float* __restrict__ row_neg,
    float* __restrict__ row_valid) {
  const int r = blockIdx.x * 256 + threadIdx.x;
  float ps = 0.f, ns = 0.f;
#pragma unroll
  for (int b = 0; b < NB; ++b) {
    ps += ppPart[b * N + r];
    ns += npPart[b * N + r];
  }
  const float mp = mpF[r], mx = mnF[r];
  const bool valid = (mp < 1e8f) && (mx > -1e8f) && (ps > 0.f) && (ns > 0.f);
  row_pos[r] = valid ? (log1pf(ps) * (1.0f / POS_W)) : 0.f;
  row_neg[r] = valid ? (log1pf(ns) * (1.0f / NEG_W)) : 0.f;
  row_valid[r] = valid ? 1.f : 0.f;
}

// ---------------- K5: final reduction ----------------
__global__ __launch_bounds__(256) void k_final(const float* __restrict__ rp,
                                               const float* __restrict__ rn,
                                               const float* __restrict__ rv,
                                               float* __restrict__ out) {
  __shared__ float red[3][4];
  const int t = threadIdx.x, wv = t >> 6, lane = t & 63;
  float sp = 0.f, sn = 0.f, sc = 0.f;
  for (int i = t; i < N; i += 256) { sp += rp[i]; sn += rn[i]; sc += rv[i]; }
#pragma unroll
  for (int off = 32; off; off >>= 1) {
    sp += __shfl_xor(sp, off);
    sn += __shfl_xor(sn, off);
    sc += __shfl_xor(sc, off);
  }
  if (lane == 0) { red[0][wv] = sp; red[1][wv] = sn; red[2][wv] = sc; }
  __syncthreads();
  if (t == 0) {
    const float tp = red[0][0] + red[0][1] + red[0][2] + red[0][3];
    const float tn = red[1][0] + red[1][1] + red[1][2] + red[1][3];
    const float tc = red[2][0] + red[2][1] + red[2][2] + red[2][3];
    const float cnt = fmaxf(tc, 1.f);
    const float pm = tp / cnt, nm = tn / cnt;
    out[0] = pm + nm;
    out[1] = pm;
    out[2] = nm;
  }
}

extern "C" void kernel_launch(void* const* d_in, const int* in_sizes, int n_in,
                              void* d_out, int out_size, void* d_ws, size_t ws_size,
                              hipStream_t stream) {
  const float* batch = (const float*)d_in[0];
  const int* labels = (const int*)d_in[1];
  float* out = (float*)d_out;

  char* ws = (char*)d_ws;
  ushort* xn = (ushort*)ws;                             // N*D bf16 = 1 MB
  float* pminPart = (float*)(ws + (size_t)N * D * 2);   // NB*N
  float* nmaxPart = pminPart + (size_t)NB * N;          // NB*N
  float* ppPart = nmaxPart + (size_t)NB * N;            // NB*N
  float* npPart = ppPart + (size_t)NB * N;              // NB*N
  float* mpF = npPart + (size_t)NB * N;                 // N
  float* mnF = mpF + N;                                 // N
  float* row_pos = mnF + N;                             // N
  float* row_neg = row_pos + N;                         // N
  float* row_valid = row_neg + N;                       // N

  k_norm<<<N / 16, 512, 0, stream>>>(batch, xn);
  k_pass<0><<<256, 512, 0, stream>>>(xn, labels, pminPart, nmaxPart, ppPart, npPart, mpF, mnF);
  k_pass<1><<<256, 512, 0, stream>>>(xn, labels, pminPart, nmaxPart, ppPart, npPart, mpF, mnF);
  k_rowterms<<<NB, 256, 0, stream>>>(ppPart, npPart, mpF, mnF, row_pos, row_neg, row_valid);
  k_final<<<1, 256, 0, stream>>>(row_pos, row_neg, row_valid, out);
}